// Round 7
// baseline (184.102 us; speedup 1.0000x reference)
//
#include <hip/hip_runtime.h>

typedef __attribute__((ext_vector_type(8))) short short8;
typedef __attribute__((ext_vector_type(4))) short s16x4;
typedef __attribute__((ext_vector_type(4))) float f32x4;

#define MFMA16(a,b,c) __builtin_amdgcn_mfma_f32_16x16x32_bf16((a),(b),(c),0,0,0)

__device__ __forceinline__ ushort f2bf(float f){ union{float f; unsigned u;} v; v.f=f; unsigned r=v.u + 0x7fffu + ((v.u>>16)&1u); return (ushort)(r>>16); }
__device__ __forceinline__ float bf2f(ushort u){ union{unsigned u; float f;} v; v.u = ((unsigned)u)<<16; return v.f; }

// ---------------------------------------------------------------------------
// prep: fused S-convert + W-transpose.
// blocks [0,1024): S fp32->bf16, 3 f32x4/thread.
// blocks [1024,1072): W [256][768] fp32 -> Wt [768][256] bf16, 64x64 tiles.
// ---------------------------------------------------------------------------
__global__ void __launch_bounds__(256) prep(const float* __restrict__ S,
    ushort* __restrict__ Sb, const float* __restrict__ W, ushort* __restrict__ Wt)
{
    __shared__ __align__(16) ushort tile[64*72];
    const int t = threadIdx.x;
    if (blockIdx.x < 1024){
        const int tid = blockIdx.x*256 + t;     // 262144 threads
#pragma unroll
        for (int r=0;r<3;r++){
            const int idx = tid + r*262144;
            f32x4 v = ((const f32x4*)S)[idx];
            s16x4 o;
            o[0]=(short)f2bf(v[0]); o[1]=(short)f2bf(v[1]);
            o[2]=(short)f2bf(v[2]); o[3]=(short)f2bf(v[3]);
            ((s16x4*)Sb)[idx] = o;
        }
    } else {
        const int i = blockIdx.x - 1024;        // 48 tiles: 4 x 12
        const int r0 = (i&3)*64, c0 = (i>>2)*64;
        const int rr = t>>2, g = (t&3)*16;
        const float* sp = W + (size_t)(r0+rr)*768 + c0 + g;
#pragma unroll
        for (int j=0;j<16;j++) tile[(g+j)*72 + rr] = f2bf(sp[j]);
        __syncthreads();
        ushort* dp = Wt + (size_t)(c0+rr)*256 + r0 + g;
        *(short8*)dp     = *(const short8*)&tile[rr*72 + g];
        *(short8*)(dp+8) = *(const short8*)&tile[rr*72 + g + 8];
    }
}

// ---------------------------------------------------------------------------
// QKV projection, v2: A-panel hoisted to REGISTERS (16 loads in flight at
// block start -- was 16 serial per-kc global-load latency exposures/wave;
// Q/K and V branches read the SAME Sb rows so one prefetch serves both),
// B panel staged in LDS. grid = (96,12), block = 256 (4 waves).
// ---------------------------------------------------------------------------
__global__ void __launch_bounds__(256) qkv_gemm(const ushort* __restrict__ Sb,
    const ushort* __restrict__ Wt, const float* __restrict__ bias,
    ushort* __restrict__ Q, ushort* __restrict__ K, ushort* __restrict__ Vt)
{
    __shared__ __align__(16) ushort Bl[64*264];
    const int t = threadIdx.x, w = t>>6, l = t&63, lr = l&15, lq = l>>4;
    const int m0 = blockIdx.x*128, n0 = blockIdx.y*64;

    // A prefetch: wave's 32 Sb rows, all 16 fragments issued up front
    const ushort* ap = Sb + (size_t)(m0 + w*32 + lr)*256 + lq*8;
    short8 sa[2][8];
#pragma unroll
    for (int g=0;g<2;g++)
#pragma unroll
        for (int kc=0;kc<8;kc++)
            sa[g][kc] = *(const short8*)(ap + g*16*256 + kc*32);

    // stage Wt rows [n0, n0+64) x 256 cols
#pragma unroll
    for (int s=0;s<8;s++){
        const int u = t + s*256, row = u>>5, c8 = u&31;
        *(short8*)&Bl[row*264 + c8*8] = *(const short8*)(Wt + (size_t)(n0+row)*256 + c8*8);
    }
    __syncthreads();

    if (n0 < 512){
        // ---- Q / K path: D[atom][col] ----
        f32x4 acc[2][4];
#pragma unroll
        for (int a=0;a<2;a++)
#pragma unroll
            for (int b2=0;b2<4;b2++) acc[a][b2]=(f32x4){0.f,0.f,0.f,0.f};
#pragma unroll
        for (int kc=0;kc<8;kc++){
#pragma unroll
            for (int nt=0;nt<4;nt++){
                short8 bf = *(const short8*)&Bl[(nt*16+lr)*264 + lq*8 + kc*32];
                acc[0][nt] = MFMA16(sa[0][kc], bf, acc[0][nt]);
                acc[1][nt] = MFMA16(sa[1][kc], bf, acc[1][nt]);
            }
        }
        ushort* dst = (n0 < 256) ? Q : K;
        const int colbase = n0 & 255;
#pragma unroll
        for (int nt=0;nt<4;nt++){
            float bv = bias[n0 + nt*16 + lr];
#pragma unroll
            for (int mt=0;mt<2;mt++){
                const int row = m0 + w*32 + mt*16 + lq*4;
                ushort* o = dst + (size_t)row*256 + colbase + nt*16 + lr;
#pragma unroll
                for (int i=0;i<4;i++) o[(size_t)i*256] = f2bf(acc[mt][nt][i] + bv);
            }
        }
    } else {
        // ---- V path: D[feature][atom] = V^T tile -> Vt[256][12288] ----
        const int f0 = n0 - 512;
        f32x4 acc[4][2];
#pragma unroll
        for (int a=0;a<4;a++)
#pragma unroll
            for (int b2=0;b2<2;b2++) acc[a][b2]=(f32x4){0.f,0.f,0.f,0.f};
#pragma unroll
        for (int kc=0;kc<8;kc++){
#pragma unroll
            for (int ft=0;ft<4;ft++){
                short8 af = *(const short8*)&Bl[(ft*16+lr)*264 + lq*8 + kc*32];
                acc[ft][0] = MFMA16(af, sa[0][kc], acc[ft][0]);
                acc[ft][1] = MFMA16(af, sa[1][kc], acc[ft][1]);
            }
        }
#pragma unroll
        for (int ft=0;ft<4;ft++){
#pragma unroll
            for (int at=0;at<2;at++){
                ushort* o = Vt + (size_t)(f0 + ft*16 + lq*4)*12288 + m0 + w*32 + at*16 + lr;
#pragma unroll
                for (int i=0;i<4;i++){
                    float bv = bias[512 + f0 + ft*16 + lq*4 + i];
                    o[(size_t)i*12288] = f2bf(acc[ft][at][i] + bv);
                }
            }
        }
    }
}

// ---------------------------------------------------------------------------
// Attention partials, v8 = r5's proven loop (__syncthreads, K+V reg prefetch,
// no setprio/raw barriers -- r6 A/B showed those cost 15us) with PIECE as a
// template param. PL=8 (piece 256) -> grid 644, ~2.5 blocks/CU (the one lever
// that moved the loop r0-r6); PL=9 (piece 512) -> grid 334 (= r5 exactly).
// Total LDS work is piece-invariant (block-chunks = sum nb^2/4096).
// MODE 0: plain bf16 partial stores; MODE 1: atomicAdd fallback.
// ---------------------------------------------------------------------------
template<int MODE, int PL>
__global__ void __launch_bounds__(256,2) attn_partial(const ushort* __restrict__ Qb,
    const ushort* __restrict__ Kb, const ushort* __restrict__ Vt,
    void* __restrict__ Optr, float* __restrict__ Lptr)
{
    __shared__ __align__(16) ushort Kl[32*264];   // 32 keys x 256 d (+8 pad)
    __shared__ __align__(16) ushort Vl[256*40];   // 256 feat x 32 keys (+8)
    __shared__ __align__(16) ushort Pl[4][32*40]; // per-wave 32x32 P round-trip
    const int t = threadIdx.x, w = t>>6, l = t&63, lr = l&15, lq = l>>4;
    constexpr int PIECE = 1 << PL;

    // map blockIdx -> (q0, kstart, kend, pbase); pbase accumulated in-scan
    const int offs[9] = {0,2048,3584,4608,6656,7168,8960,10240,12288};
    int bi = blockIdx.x, q0=0, kstart=0, kend=0, off=0, nbg=0, pbase=0, pb=0;
#pragma unroll
    for (int s=0;s<8;s++){
        const int nb = offs[s+1]-offs[s];
        const int tiles = nb>>7, pieces = (nb + PIECE-1)>>PL;
        const int items = tiles*pieces;
        if (bi >= 0 && bi < items){
            const int tile = bi / pieces, piece = bi - tile*pieces;
            q0 = offs[s] + tile*128;
            kstart = offs[s] + piece*PIECE;
            kend = min(offs[s]+nb, kstart+PIECE);
            off = offs[s]; nbg = nb; pbase = pb;
        }
        bi -= items;
        pb += nb*pieces;
    }
    const int nchunks = (kend - kstart) >> 5;
    const int pc = (kstart - off) >> PL;         // piece index within graph

    // Q fragments: wave owns rows q0 + w*32 .. +31 (2 groups of 16)
    short8 qf[2][8];
#pragma unroll
    for (int g=0;g<2;g++){
        const ushort* qp = Qb + (size_t)(q0 + w*32 + g*16 + lr)*256 + lq*8;
#pragma unroll
        for (int kc=0;kc<8;kc++) qf[g][kc] = *(const short8*)(qp + kc*32);
    }
    f32x4 Oa[2][16];
#pragma unroll
    for (int g=0;g<2;g++)
#pragma unroll
        for (int ft=0;ft<16;ft++) Oa[g][ft] = (f32x4){0.f,0.f,0.f,0.f};
    float l_lane[2][4] = {{0.f,0.f,0.f,0.f},{0.f,0.f,0.f,0.f}};

    // staging addresses + prologue prefetch of chunk 0 (K and V)
    const int kr = t>>5, kcol = t&31;            // K: rows kr+s*8, 16B col kcol
    const ushort* kg0 = Kb + (size_t)(kstart + kr)*256 + kcol*8;
    const ushort* vg0 = Vt + (size_t)t*12288 + kstart;  // V: feat row t, 64B
    short8 kreg[4], vreg[4];
#pragma unroll
    for (int s=0;s<4;s++){
        kreg[s] = *(const short8*)(kg0 + (size_t)s*8*256);
        vreg[s] = *(const short8*)(vg0 + s*8);
    }

    for (int ck=0; ck<nchunks; ck++){
        // drain prefetch into LDS (vmcnt wait lands here; latency was covered
        // by the previous chunk's compute)
#pragma unroll
        for (int s=0;s<4;s++)
            *(short8*)&Kl[(kr + s*8)*264 + kcol*8] = kreg[s];
#pragma unroll
        for (int s=0;s<4;s++)
            *(short8*)&Vl[t*40 + s*8] = vreg[s];
        // issue next chunk's loads; in flight across the barrier
        if (ck+1 < nchunks){
            const ushort* kg = kg0 + (size_t)(ck+1)*32*256;
            const ushort* vg = vg0 + (ck+1)*32;
#pragma unroll
            for (int s=0;s<4;s++){
                kreg[s] = *(const short8*)(kg + (size_t)s*8*256);
                vreg[s] = *(const short8*)(vg + s*8);
            }
        }
        __syncthreads();

        // S = Q K^T (32 queries x 32 keys per wave)
        f32x4 sc[2][2];
#pragma unroll
        for (int g=0;g<2;g++)
#pragma unroll
            for (int h=0;h<2;h++) sc[g][h] = (f32x4){0.f,0.f,0.f,0.f};
#pragma unroll
        for (int kc=0;kc<8;kc++){
            short8 b0 = *(const short8*)&Kl[ lr     *264 + kc*32 + lq*8];
            short8 b1 = *(const short8*)&Kl[(16+lr)*264 + kc*32 + lq*8];
#pragma unroll
            for (int g=0;g<2;g++){
                sc[g][0] = MFMA16(qf[g][kc], b0, sc[g][0]);
                sc[g][1] = MFMA16(qf[g][kc], b1, sc[g][1]);
            }
        }
        // p = exp(s/16) = exp2(s * log2(e)/16); scores ~N(0,1): safe
        ushort* pw = &Pl[w][0];
#pragma unroll
        for (int g=0;g<2;g++)
#pragma unroll
            for (int i=0;i<4;i++){
                float p0 = exp2f(sc[g][0][i]*0.0901684284f);
                float p1 = exp2f(sc[g][1][i]*0.0901684284f);
                l_lane[g][i] += p0 + p1;
                pw[(g*16+lq*4+i)*40 + lr]      = f2bf(p0);
                pw[(g*16+lq*4+i)*40 + 16 + lr] = f2bf(p1);
            }
        __asm__ volatile("s_waitcnt lgkmcnt(0)" ::: "memory");
        short8 pf0 = *(const short8*)&pw[ lr     *40 + lq*8];
        short8 pf1 = *(const short8*)&pw[(16+lr)*40 + lq*8];

        // O += P V  (16 feature tiles, V-frag shared across both q-groups)
#pragma unroll
        for (int ft=0;ft<16;ft++){
            short8 vf = *(const short8*)&Vl[(ft*16+lr)*40 + lq*8];
            Oa[0][ft] = MFMA16(pf0, vf, Oa[0][ft]);
            Oa[1][ft] = MFMA16(pf1, vf, Oa[1][ft]);
        }
        __syncthreads();
    }

    // reduce l across the 16 key-lanes of each row group
#pragma unroll
    for (int g=0;g<2;g++)
#pragma unroll
        for (int i=0;i<4;i++){
            float r = l_lane[g][i];
            r += __shfl_xor(r,1); r += __shfl_xor(r,2);
            r += __shfl_xor(r,4); r += __shfl_xor(r,8);
            l_lane[g][i] = r;
        }

    if constexpr (MODE == 0){
        // plain bf16 partial stores: row = pbase + pc*nbg + (q - off)
        ushort* Op = (ushort*)Optr;
        const int prow0 = pbase + pc*nbg + (q0 + w*32 - off);
#pragma unroll
        for (int g=0;g<2;g++)
#pragma unroll
            for (int i=0;i<4;i++){
                ushort* o = Op + (size_t)(prow0 + g*16 + lq*4 + i)*256 + lr;
#pragma unroll
                for (int ft=0;ft<16;ft++) o[ft*16] = f2bf(Oa[g][ft][i]);
            }
        if (lr == 0){
#pragma unroll
            for (int g=0;g<2;g++)
#pragma unroll
                for (int i=0;i<4;i++)
                    Lptr[prow0 + g*16 + lq*4 + i] = l_lane[g][i];
        }
    } else {
        // fallback: atomic accumulate into out/lsum
        float* out = (float*)Optr;
#pragma unroll
        for (int g=0;g<2;g++){
            float* op = out + (size_t)(q0 + w*32 + g*16 + lq*4)*256 + lr;
#pragma unroll
            for (int i=0;i<4;i++)
#pragma unroll
                for (int ft=0;ft<16;ft++)
                    atomicAdd(&op[(size_t)i*256 + ft*16], Oa[g][ft][i]);
        }
        if (lr == 0){
#pragma unroll
            for (int g=0;g<2;g++)
#pragma unroll
                for (int i=0;i<4;i++)
                    atomicAdd(&Lptr[q0 + w*32 + g*16 + lq*4 + i], l_lane[g][i]);
        }
    }
}

// ---------------------------------------------------------------------------
// Fused reduce + normalize (MODE 0): out[q][f] = sum_p O_p[q][f] / sum_p L_p[q].
// 1536 blocks x 256 threads; 8 rows/block, 32 threads/row (8 feat each).
// Piece count/layout derived at runtime from PL.
// ---------------------------------------------------------------------------
__global__ void __launch_bounds__(256) reduce_norm(const ushort* __restrict__ Opart,
    const float* __restrict__ Lpart, float* __restrict__ out, int PL)
{
    const int offs[9] = {0,2048,3584,4608,6656,7168,8960,10240,12288};
    const int t = threadIdx.x;
    const int row = blockIdx.x*8 + (t>>5);
    const int f = (t&31)*8;
    const int PIECE = 1 << PL;
    int s = 0, pbase = 0, pb = 0, nb = 0, S = 0, base = 0;
#pragma unroll
    for (int i=0;i<8;i++){
        const int nbi = offs[i+1]-offs[i];
        const int pieces = (nbi + PIECE-1) >> PL;
        if (row >= offs[i] && row < offs[i+1]){
            nb = nbi; S = pieces; pbase = pb; base = pb + (row - offs[i]);
        }
        pb += nbi*pieces;
    }
    (void)pbase; (void)s;
    float acc[8] = {0.f,0.f,0.f,0.f,0.f,0.f,0.f,0.f};
    float L = 0.f;
    for (int p=0; p<S; p++){
        const size_t pr = (size_t)(base + p*nb);
        L += Lpart[pr];
        short8 v = *(const short8*)&Opart[pr*256 + f];
#pragma unroll
        for (int j=0;j<8;j++) acc[j] += bf2f((ushort)v[j]);
    }
    const float inv = 1.0f / L;
    f32x4 o0, o1;
#pragma unroll
    for (int j=0;j<4;j++){ o0[j] = acc[j]*inv; o1[j] = acc[4+j]*inv; }
    float* op = out + (size_t)row*256 + f;
    *(f32x4*)op     = o0;
    *(f32x4*)(op+4) = o1;
}

// ---------------------------------------------------------------------------
// Normalize (MODE 1 fallback): out[row][:] /= lsum[row].
// ---------------------------------------------------------------------------
__global__ void __launch_bounds__(256) normalize_out(float* __restrict__ out,
    const float* __restrict__ lsum)
{
    const int row = blockIdx.x, t = threadIdx.x;
    const float inv = 1.0f / lsum[row];
    out[(size_t)row*256 + t] *= inv;
}

// ---------------------------------------------------------------------------
extern "C" void kernel_launch(void* const* d_in, const int* in_sizes, int n_in,
                              void* d_out, int out_size, void* d_ws, size_t ws_size,
                              hipStream_t stream)
{
    // Match input roles by unique flat element counts (order-proof):
    const float* S    = nullptr;
    const float* W    = nullptr;
    const float* bias = nullptr;
    for (int i = 0; i < n_in; i++){
        if      (in_sizes[i] == 3145728) S    = (const float*)d_in[i];
        else if (in_sizes[i] ==  196608) W    = (const float*)d_in[i];
        else if (in_sizes[i] ==     768) bias = (const float*)d_in[i];
    }
    if (!S)    S    = (const float*)d_in[0];
    if (!W)    W    = (const float*)d_in[1];
    if (!bias) bias = (const float*)d_in[2];

    float* out = (float*)d_out;          // [12288,256] fp32 result

    ushort* ws  = (ushort*)d_ws;
    ushort* Wt  = ws;                    // [768,256]    bf16
    ushort* Qb  = Wt + 768*256;          // [12288,256]  bf16
    ushort* Kb  = Qb + 12288*256;        // [12288,256]  bf16
    ushort* Vtb = Kb + 12288*256;        // [256,12288]  bf16

    const size_t base_b = ((size_t)768*256 + 3*(size_t)12288*256) * 2;   // 19,267,584
    // piece=256: 82432 partial rows; piece=512: 42752 partial rows
    const size_t need256 = base_b + (size_t)82432*512 + (size_t)82432*4; // 61,802,496
    const size_t need512 = base_b + (size_t)42752*512 + (size_t)42752*4; // 41,327,616

    // Sb (bf16 S) staged in d_out's first 6 MB; consumed by qkv_gemm, then
    // d_out is rewritten by reduce_norm / attention (stream-ordered).
    ushort* Sb = (ushort*)d_out;

    prep     <<<1072,        256, 0, stream>>>(S, Sb, W, Wt);
    qkv_gemm <<<dim3(96,12), 256, 0, stream>>>(Sb, Wt, bias, Qb, Kb, Vtb);

    if (ws_size >= need256){
        ushort* Opart = (ushort*)((char*)d_ws + base_b);
        float*  Lpart = (float*)((char*)d_ws + base_b + (size_t)82432*512);
        attn_partial<0,8><<<644, 256, 0, stream>>>(Qb, Kb, Vtb, (void*)Opart, Lpart);
        reduce_norm      <<<1536, 256, 0, stream>>>(Opart, Lpart, out, 8);
    } else if (ws_size >= need512){
        ushort* Opart = (ushort*)((char*)d_ws + base_b);
        float*  Lpart = (float*)((char*)d_ws + base_b + (size_t)42752*512);
        attn_partial<0,9><<<334, 256, 0, stream>>>(Qb, Kb, Vtb, (void*)Opart, Lpart);
        reduce_norm      <<<1536, 256, 0, stream>>>(Opart, Lpart, out, 9);
    } else {
        float* lsum = (float*)((char*)d_ws + base_b);
        (void)hipMemsetAsync(d_out, 0, (size_t)12288*256*4, stream);
        (void)hipMemsetAsync(lsum,  0, (size_t)12288*4,     stream);
        attn_partial<1,9><<<334, 256, 0, stream>>>(Qb, Kb, Vtb, (void*)out, lsum);
        normalize_out    <<<12288, 256, 0, stream>>>(out, lsum);
    }
}

// Round 8
// 158.737 us; speedup vs baseline: 1.1598x; 1.1598x over previous
//
#include <hip/hip_runtime.h>

typedef __attribute__((ext_vector_type(8))) short short8;
typedef __attribute__((ext_vector_type(4))) short s16x4;
typedef __attribute__((ext_vector_type(4))) float f32x4;

#define MFMA16(a,b,c) __builtin_amdgcn_mfma_f32_16x16x32_bf16((a),(b),(c),0,0,0)

__device__ __forceinline__ ushort f2bf(float f){ union{float f; unsigned u;} v; v.f=f; unsigned r=v.u + 0x7fffu + ((v.u>>16)&1u); return (ushort)(r>>16); }
__device__ __forceinline__ float bf2f(ushort u){ union{unsigned u; float f;} v; v.u = ((unsigned)u)<<16; return v.f; }

// ---------------------------------------------------------------------------
// prep: fused S-convert + W-transpose.
// ---------------------------------------------------------------------------
__global__ void __launch_bounds__(256) prep(const float* __restrict__ S,
    ushort* __restrict__ Sb, const float* __restrict__ W, ushort* __restrict__ Wt)
{
    __shared__ __align__(16) ushort tile[64*72];
    const int t = threadIdx.x;
    if (blockIdx.x < 1024){
        const int tid = blockIdx.x*256 + t;
#pragma unroll
        for (int r=0;r<3;r++){
            const int idx = tid + r*262144;
            f32x4 v = ((const f32x4*)S)[idx];
            s16x4 o;
            o[0]=(short)f2bf(v[0]); o[1]=(short)f2bf(v[1]);
            o[2]=(short)f2bf(v[2]); o[3]=(short)f2bf(v[3]);
            ((s16x4*)Sb)[idx] = o;
        }
    } else {
        const int i = blockIdx.x - 1024;        // 48 tiles: 4 x 12
        const int r0 = (i&3)*64, c0 = (i>>2)*64;
        const int rr = t>>2, g = (t&3)*16;
        const float* sp = W + (size_t)(r0+rr)*768 + c0 + g;
#pragma unroll
        for (int j=0;j<16;j++) tile[(g+j)*72 + rr] = f2bf(sp[j]);
        __syncthreads();
        ushort* dp = Wt + (size_t)(c0+rr)*256 + r0 + g;
        *(short8*)dp     = *(const short8*)&tile[rr*72 + g];
        *(short8*)(dp+8) = *(const short8*)&tile[rr*72 + g + 8];
    }
}

// ---------------------------------------------------------------------------
// QKV projection: A-panel register-hoisted, B panel LDS-staged.
// grid = (96,12), block = 256 (4 waves).
// ---------------------------------------------------------------------------
__global__ void __launch_bounds__(256) qkv_gemm(const ushort* __restrict__ Sb,
    const ushort* __restrict__ Wt, const float* __restrict__ bias,
    ushort* __restrict__ Q, ushort* __restrict__ K, ushort* __restrict__ Vt)
{
    __shared__ __align__(16) ushort Bl[64*264];
    const int t = threadIdx.x, w = t>>6, l = t&63, lr = l&15, lq = l>>4;
    const int m0 = blockIdx.x*128, n0 = blockIdx.y*64;

    const ushort* ap = Sb + (size_t)(m0 + w*32 + lr)*256 + lq*8;
    short8 sa[2][8];
#pragma unroll
    for (int g=0;g<2;g++)
#pragma unroll
        for (int kc=0;kc<8;kc++)
            sa[g][kc] = *(const short8*)(ap + g*16*256 + kc*32);

#pragma unroll
    for (int s=0;s<8;s++){
        const int u = t + s*256, row = u>>5, c8 = u&31;
        *(short8*)&Bl[row*264 + c8*8] = *(const short8*)(Wt + (size_t)(n0+row)*256 + c8*8);
    }
    __syncthreads();

    if (n0 < 512){
        f32x4 acc[2][4];
#pragma unroll
        for (int a=0;a<2;a++)
#pragma unroll
            for (int b2=0;b2<4;b2++) acc[a][b2]=(f32x4){0.f,0.f,0.f,0.f};
#pragma unroll
        for (int kc=0;kc<8;kc++){
#pragma unroll
            for (int nt=0;nt<4;nt++){
                short8 bf = *(const short8*)&Bl[(nt*16+lr)*264 + lq*8 + kc*32];
                acc[0][nt] = MFMA16(sa[0][kc], bf, acc[0][nt]);
                acc[1][nt] = MFMA16(sa[1][kc], bf, acc[1][nt]);
            }
        }
        ushort* dst = (n0 < 256) ? Q : K;
        const int colbase = n0 & 255;
#pragma unroll
        for (int nt=0;nt<4;nt++){
            float bv = bias[n0 + nt*16 + lr];
#pragma unroll
            for (int mt=0;mt<2;mt++){
                const int row = m0 + w*32 + mt*16 + lq*4;
                ushort* o = dst + (size_t)row*256 + colbase + nt*16 + lr;
#pragma unroll
                for (int i=0;i<4;i++) o[(size_t)i*256] = f2bf(acc[mt][nt][i] + bv);
            }
        }
    } else {
        const int f0 = n0 - 512;
        f32x4 acc[4][2];
#pragma unroll
        for (int a=0;a<4;a++)
#pragma unroll
            for (int b2=0;b2<2;b2++) acc[a][b2]=(f32x4){0.f,0.f,0.f,0.f};
#pragma unroll
        for (int kc=0;kc<8;kc++){
#pragma unroll
            for (int ft=0;ft<4;ft++){
                short8 af = *(const short8*)&Bl[(ft*16+lr)*264 + lq*8 + kc*32];
                acc[ft][0] = MFMA16(af, sa[0][kc], acc[ft][0]);
                acc[ft][1] = MFMA16(af, sa[1][kc], acc[ft][1]);
            }
        }
#pragma unroll
        for (int ft=0;ft<4;ft++){
#pragma unroll
            for (int at=0;at<2;at++){
                ushort* o = Vt + (size_t)(f0 + ft*16 + lq*4)*12288 + m0 + w*32 + at*16 + lr;
#pragma unroll
                for (int i=0;i<4;i++){
                    float bv = bias[512 + f0 + ft*16 + lq*4 + i];
                    o[(size_t)i*12288] = f2bf(acc[ft][at][i] + bv);
                }
            }
        }
    }
}

// ---------------------------------------------------------------------------
// Attention partials, v9: SWAPPED QK^T + IN-REGISTER softmax/P (T12-class).
// S^T = MFMA(K,Q): lane holds 8 scores of its OWN query lr -> exp in regs,
// redistribute bf16-packed P across lq-groups with 16 ds_bpermute. Deletes
// the per-chunk {16 scalar ds_write + lgkmcnt(0) fence + 2 ds_read} P
// round-trip that has been the untouched serialization point of r0-r7.
// Geometry = r5 (Qtile=128, piece=512, grid 334, K+V reg prefetch,
// __syncthreads). Pl LDS freed (47.6 -> 37.4 KB).
// MODE 0: plain bf16 partial stores; MODE 1: atomicAdd fallback.
// ---------------------------------------------------------------------------
template<int MODE>
__global__ void __launch_bounds__(256,2) attn_partial(const ushort* __restrict__ Qb,
    const ushort* __restrict__ Kb, const ushort* __restrict__ Vt,
    void* __restrict__ Optr, float* __restrict__ Lptr)
{
    __shared__ __align__(16) ushort Kl[32*264];   // 32 keys x 256 d (+8 pad)
    __shared__ __align__(16) ushort Vl[256*40];   // 256 feat x 32 keys (+8)
    const int t = threadIdx.x, w = t>>6, l = t&63, lr = l&15, lq = l>>4;

    const int offs[9] = {0,2048,3584,4608,6656,7168,8960,10240,12288};
    int bi = blockIdx.x, q0=0, kstart=0, kend=0, off=0, nbg=0, pbase=0, pb=0;
#pragma unroll
    for (int s=0;s<8;s++){
        const int nb = offs[s+1]-offs[s];
        const int tiles = nb>>7, pieces = (nb+511)>>9;
        const int items = tiles*pieces;
        if (bi >= 0 && bi < items){
            const int tile = bi / pieces, piece = bi - tile*pieces;
            q0 = offs[s] + tile*128;
            kstart = offs[s] + piece*512;
            kend = min(offs[s]+nb, kstart+512);
            off = offs[s]; nbg = nb; pbase = pb;
        }
        bi -= items;
        pb += nb*pieces;
    }
    const int nchunks = (kend - kstart) >> 5;
    const int pc = (kstart - off) >> 9;

    // Q fragments (used as MFMA *B* operand after the swap; same layout)
    short8 qf[2][8];
#pragma unroll
    for (int g=0;g<2;g++){
        const ushort* qp = Qb + (size_t)(q0 + w*32 + g*16 + lr)*256 + lq*8;
#pragma unroll
        for (int kc=0;kc<8;kc++) qf[g][kc] = *(const short8*)(qp + kc*32);
    }
    f32x4 Oa[2][16];
#pragma unroll
    for (int g=0;g<2;g++)
#pragma unroll
        for (int ft=0;ft<16;ft++) Oa[g][ft] = (f32x4){0.f,0.f,0.f,0.f};
    float l_lane[2] = {0.f, 0.f};                 // per-lane l of query g*16+lr

    // staging addresses + prologue prefetch of chunk 0 (K and V)
    const int kr = t>>5, kcol = t&31;
    const ushort* kg0 = Kb + (size_t)(kstart + kr)*256 + kcol*8;
    const ushort* vg0 = Vt + (size_t)t*12288 + kstart;
    short8 kreg[4], vreg[4];
#pragma unroll
    for (int s=0;s<4;s++){
        kreg[s] = *(const short8*)(kg0 + (size_t)s*8*256);
        vreg[s] = *(const short8*)(vg0 + s*8);
    }

    // bpermute routing (constant per lane): target lane (lr,lq) gathers keys
    // 8lq..8lq+7 from source lanes L0 = lr+32*(lq&1), L1 = L0+16; hi words
    // (keys 16..31) when lq>=2.
    const int i0 = 4*(lr + 32*(lq&1));
    const int i1 = i0 + 64;
    const bool hi = (lq >= 2);

    for (int ck=0; ck<nchunks; ck++){
#pragma unroll
        for (int s=0;s<4;s++)
            *(short8*)&Kl[(kr + s*8)*264 + kcol*8] = kreg[s];
#pragma unroll
        for (int s=0;s<4;s++)
            *(short8*)&Vl[t*40 + s*8] = vreg[s];
        if (ck+1 < nchunks){
            const ushort* kg = kg0 + (size_t)(ck+1)*32*256;
            const ushort* vg = vg0 + (ck+1)*32;
#pragma unroll
            for (int s=0;s<4;s++){
                kreg[s] = *(const short8*)(kg + (size_t)s*8*256);
                vreg[s] = *(const short8*)(vg + s*8);
            }
        }
        __syncthreads();

        // S^T = K Q^T: sc[h][g] rows = keys h*16+lq*4+i, col = query g*16+lr
        f32x4 sc[2][2];
#pragma unroll
        for (int h=0;h<2;h++)
#pragma unroll
            for (int g=0;g<2;g++) sc[h][g] = (f32x4){0.f,0.f,0.f,0.f};
#pragma unroll
        for (int kc=0;kc<8;kc++){
            short8 b0 = *(const short8*)&Kl[ lr     *264 + kc*32 + lq*8];
            short8 b1 = *(const short8*)&Kl[(16+lr)*264 + kc*32 + lq*8];
#pragma unroll
            for (int g=0;g<2;g++){
                sc[0][g] = MFMA16(b0, qf[g][kc], sc[0][g]);
                sc[1][g] = MFMA16(b1, qf[g][kc], sc[1][g]);
            }
        }

        // in-register softmax + P redistribution (keys of my query lr)
        short8 pa[2];
#pragma unroll
        for (int g=0;g<2;g++){
            float p[8];
#pragma unroll
            for (int h=0;h<2;h++)
#pragma unroll
                for (int i=0;i<4;i++){
                    float v = exp2f(sc[h][g][i]*0.0901684284f);
                    p[h*4+i] = v;
                    l_lane[g] += v;
                }
            unsigned w0 = (unsigned)f2bf(p[0]) | ((unsigned)f2bf(p[1])<<16);
            unsigned w1 = (unsigned)f2bf(p[2]) | ((unsigned)f2bf(p[3])<<16);
            unsigned w2 = (unsigned)f2bf(p[4]) | ((unsigned)f2bf(p[5])<<16);
            unsigned w3 = (unsigned)f2bf(p[6]) | ((unsigned)f2bf(p[7])<<16);
            unsigned a0 = (unsigned)__builtin_amdgcn_ds_bpermute(i0, (int)w0);
            unsigned a2 = (unsigned)__builtin_amdgcn_ds_bpermute(i0, (int)w2);
            unsigned b1w= (unsigned)__builtin_amdgcn_ds_bpermute(i0, (int)w1);
            unsigned b3 = (unsigned)__builtin_amdgcn_ds_bpermute(i0, (int)w3);
            unsigned c0 = (unsigned)__builtin_amdgcn_ds_bpermute(i1, (int)w0);
            unsigned c2 = (unsigned)__builtin_amdgcn_ds_bpermute(i1, (int)w2);
            unsigned d1 = (unsigned)__builtin_amdgcn_ds_bpermute(i1, (int)w1);
            unsigned d3 = (unsigned)__builtin_amdgcn_ds_bpermute(i1, (int)w3);
            union { unsigned u[4]; short8 s8; } pk;
            pk.u[0] = hi ? a2 : a0;
            pk.u[1] = hi ? b3 : b1w;
            pk.u[2] = hi ? c2 : c0;
            pk.u[3] = hi ? d3 : d1;
            pa[g] = pk.s8;
        }

        // O += P V  (16 feature tiles)
#pragma unroll
        for (int ft=0;ft<16;ft++){
            short8 vf = *(const short8*)&Vl[(ft*16+lr)*40 + lq*8];
            Oa[0][ft] = MFMA16(pa[0], vf, Oa[0][ft]);
            Oa[1][ft] = MFMA16(pa[1], vf, Oa[1][ft]);
        }
        __syncthreads();
    }

    // reduce l across the 4 lq-groups (each lane holds l of query g*16+lr)
#pragma unroll
    for (int g=0;g<2;g++){
        float r = l_lane[g];
        r += __shfl_xor(r,16); r += __shfl_xor(r,32);
        l_lane[g] = r;
    }

    if constexpr (MODE == 0){
        ushort* Op = (ushort*)Optr;
        const int prow0 = pbase + pc*nbg + (q0 + w*32 - off);
#pragma unroll
        for (int g=0;g<2;g++)
#pragma unroll
            for (int i=0;i<4;i++){
                ushort* o = Op + (size_t)(prow0 + g*16 + lq*4 + i)*256 + lr;
#pragma unroll
                for (int ft=0;ft<16;ft++) o[ft*16] = f2bf(Oa[g][ft][i]);
            }
        if (l < 16){
            Lptr[prow0 + lr]      = l_lane[0];
            Lptr[prow0 + 16 + lr] = l_lane[1];
        }
    } else {
        float* out = (float*)Optr;
#pragma unroll
        for (int g=0;g<2;g++){
            float* op = out + (size_t)(q0 + w*32 + g*16 + lq*4)*256 + lr;
#pragma unroll
            for (int i=0;i<4;i++)
#pragma unroll
                for (int ft=0;ft<16;ft++)
                    atomicAdd(&op[(size_t)i*256 + ft*16], Oa[g][ft][i]);
        }
        if (l < 16){
            atomicAdd(&Lptr[q0 + w*32 + lr],      l_lane[0]);
            atomicAdd(&Lptr[q0 + w*32 + 16 + lr], l_lane[1]);
        }
    }
}

// ---------------------------------------------------------------------------
// Fused reduce + normalize: out[q][f] = sum_p O_p[q][f] / sum_p L_p[q].
// 1536 blocks x 256 threads; 8 rows/block, 32 threads/row.
// ---------------------------------------------------------------------------
__global__ void __launch_bounds__(256) reduce_norm(const ushort* __restrict__ Opart,
    const float* __restrict__ Lpart, float* __restrict__ out, int PL)
{
    const int offs[9] = {0,2048,3584,4608,6656,7168,8960,10240,12288};
    const int t = threadIdx.x;
    const int row = blockIdx.x*8 + (t>>5);
    const int f = (t&31)*8;
    const int PIECE = 1 << PL;
    int pb = 0, nb = 0, S = 0, base = 0;
#pragma unroll
    for (int i=0;i<8;i++){
        const int nbi = offs[i+1]-offs[i];
        const int pieces = (nbi + PIECE-1) >> PL;
        if (row >= offs[i] && row < offs[i+1]){
            nb = nbi; S = pieces; base = pb + (row - offs[i]);
        }
        pb += nbi*pieces;
    }
    float acc[8] = {0.f,0.f,0.f,0.f,0.f,0.f,0.f,0.f};
    float L = 0.f;
    for (int p=0; p<S; p++){
        const size_t pr = (size_t)(base + p*nb);
        L += Lpart[pr];
        short8 v = *(const short8*)&Opart[pr*256 + f];
#pragma unroll
        for (int j=0;j<8;j++) acc[j] += bf2f((ushort)v[j]);
    }
    const float inv = 1.0f / L;
    f32x4 o0, o1;
#pragma unroll
    for (int j=0;j<4;j++){ o0[j] = acc[j]*inv; o1[j] = acc[4+j]*inv; }
    float* op = out + (size_t)row*256 + f;
    *(f32x4*)op     = o0;
    *(f32x4*)(op+4) = o1;
}

// ---------------------------------------------------------------------------
// Normalize (MODE 1 fallback): out[row][:] /= lsum[row].
// ---------------------------------------------------------------------------
__global__ void __launch_bounds__(256) normalize_out(float* __restrict__ out,
    const float* __restrict__ lsum)
{
    const int row = blockIdx.x, t = threadIdx.x;
    const float inv = 1.0f / lsum[row];
    out[(size_t)row*256 + t] *= inv;
}

// ---------------------------------------------------------------------------
extern "C" void kernel_launch(void* const* d_in, const int* in_sizes, int n_in,
                              void* d_out, int out_size, void* d_ws, size_t ws_size,
                              hipStream_t stream)
{
    const float* S    = nullptr;
    const float* W    = nullptr;
    const float* bias = nullptr;
    for (int i = 0; i < n_in; i++){
        if      (in_sizes[i] == 3145728) S    = (const float*)d_in[i];
        else if (in_sizes[i] ==  196608) W    = (const float*)d_in[i];
        else if (in_sizes[i] ==     768) bias = (const float*)d_in[i];
    }
    if (!S)    S    = (const float*)d_in[0];
    if (!W)    W    = (const float*)d_in[1];
    if (!bias) bias = (const float*)d_in[2];

    float* out = (float*)d_out;          // [12288,256] fp32 result

    ushort* ws  = (ushort*)d_ws;
    ushort* Wt  = ws;                    // [768,256]    bf16
    ushort* Qb  = Wt + 768*256;          // [12288,256]  bf16
    ushort* Kb  = Qb + 12288*256;        // [12288,256]  bf16
    ushort* Vtb = Kb + 12288*256;        // [256,12288]  bf16

    const size_t base_b  = ((size_t)768*256 + 3*(size_t)12288*256) * 2;   // 19,267,584
    const size_t need512 = base_b + (size_t)42752*512 + (size_t)42752*4;  // 41,327,616

    ushort* Sb = (ushort*)d_out;

    prep     <<<1072,        256, 0, stream>>>(S, Sb, W, Wt);
    qkv_gemm <<<dim3(96,12), 256, 0, stream>>>(Sb, Wt, bias, Qb, Kb, Vtb);

    if (ws_size >= need512){
        ushort* Opart = (ushort*)((char*)d_ws + base_b);
        float*  Lpart = (float*)((char*)d_ws + base_b + (size_t)42752*512);
        attn_partial<0><<<334, 256, 0, stream>>>(Qb, Kb, Vtb, (void*)Opart, Lpart);
        reduce_norm    <<<1536, 256, 0, stream>>>(Opart, Lpart, out, 9);
    } else {
        float* lsum = (float*)((char*)d_ws + base_b);
        (void)hipMemsetAsync(d_out, 0, (size_t)12288*256*4, stream);
        (void)hipMemsetAsync(lsum,  0, (size_t)12288*4,     stream);
        attn_partial<1><<<334, 256, 0, stream>>>(Qb, Kb, Vtb, (void*)out, lsum);
        normalize_out  <<<12288, 256, 0, stream>>>(out, lsum);
    }
}